// Round 1
// baseline (396.913 us; speedup 1.0000x reference)
//
#include <hip/hip_runtime.h>

// MultiCellLSTM: B=4096 independent LSTM chains, H=64, T1=512 steps,
// 3 cell types by t%4 (pattern 0,2,1,2). Each block = 16 batch rows,
// 4 waves split 256 gate cols into 16-col slices (wave w owns N-tiles
// w, w+4, w+8, w+12 -> each lane holds i,f,g,o for the same (row,col)).
// K=96 MFMA: hx[64] ++ x1,x2,x3 ++ 1.0(bias) ++ zero pad.

typedef __attribute__((ext_vector_type(4))) short short4v;
typedef __attribute__((ext_vector_type(8))) short short8v;
typedef __attribute__((ext_vector_type(4))) float float4v;

template <int N> struct IC { static constexpr int value = N; };

#define STRIDE 100  // bf16 elements per A-buffer row (96 used + pad); keeps 8B align for b64 frag loads

#if __has_builtin(__builtin_amdgcn_exp2f)
#define EXP2F(x) __builtin_amdgcn_exp2f(x)
#else
#define EXP2F(x) exp2f(x)
#endif
#if __has_builtin(__builtin_amdgcn_rcpf)
#define RCPF(x) __builtin_amdgcn_rcpf(x)
#else
#define RCPF(x) (1.0f / (x))
#endif

__device__ __forceinline__ short f2bf(float f) {
  union { float f; unsigned u; } v; v.f = f;
  unsigned r = v.u + 0x7FFFu + ((v.u >> 16) & 1u);  // RNE
  return (short)(r >> 16);
}
__device__ __forceinline__ float bf2f(short h) {
  union { float f; unsigned u; } v;
  v.u = ((unsigned)(unsigned short)h) << 16;
  return v.f;
}
__device__ __forceinline__ float fsig(float x) {
  float e = EXP2F(x * -1.4426950408889634f);
  return RCPF(1.0f + e);  // large +x: e->0 -> 1 ; large -x: e->inf -> 0
}
__device__ __forceinline__ float ftanh(float x) {
  float e = EXP2F(x * -2.8853900817779268f);
  float r = RCPF(1.0f + e);
  return __builtin_fmaf(2.0f, r, -1.0f);
}

__global__ __launch_bounds__(256, 1) void mlstm_kernel(
    const float* __restrict__ x1, const float* __restrict__ x2,
    const float* __restrict__ x3,
    const float* __restrict__ Wi3, const float* __restrict__ Wh3,
    const float* __restrict__ bi3, const float* __restrict__ bh3,
    const float* __restrict__ Wi2, const float* __restrict__ Wh2,
    const float* __restrict__ bi2, const float* __restrict__ bh2,
    const float* __restrict__ Wi1, const float* __restrict__ Wh1,
    const float* __restrict__ bi1, const float* __restrict__ bh1,
    const float* __restrict__ Wout, const float* __restrict__ bout,
    float* __restrict__ out) {
  __shared__ __attribute__((aligned(16))) short A0[16 * STRIDE];
  __shared__ __attribute__((aligned(16))) short A1[16 * STRIDE];
  __shared__ short x1b[16 * 512];
  __shared__ short x2b[16 * 256];
  __shared__ short x3b[16 * 128];

  const int tid = threadIdx.x;
  const int wid = tid >> 6;   // wave id 0..3 = gate-col slice
  const int lane = tid & 63;
  const int q = lane >> 4;    // quad
  const int c = lane & 15;
  const int R0 = blockIdx.x << 4;  // 16 batch rows per block

  // ---- preload x into LDS as bf16 (one-time; coalesced) ----
  for (int idx = tid; idx < 16 * 512; idx += 256) {
    int m = idx >> 9, t = idx & 511;
    x1b[idx] = f2bf(x1[(size_t)(R0 + m) * 512 + t]);
  }
  for (int idx = tid; idx < 16 * 256; idx += 256) {
    int m = idx >> 8, t = idx & 255;
    x2b[idx] = f2bf(x2[(size_t)(R0 + m) * 256 + t]);
  }
  for (int idx = tid; idx < 16 * 128; idx += 256) {
    int m = idx >> 7, t = idx & 127;
    x3b[idx] = f2bf(x3[(size_t)(R0 + m) * 128 + t]);
  }

  // ---- init A buffers: hx=0, col67 = 1.0 (bias lane), rest 0 ----
  for (int idx = tid; idx < 16 * STRIDE; idx += 256) {
    int col = idx % STRIDE;
    short v = (col == 67) ? (short)0x3F80 : (short)0;
    A0[idx] = v;
    A1[idx] = v;
  }

  // ---- pack weight B-fragments into registers ----
  // B[k][n]: n = lane&15 (within tile), k = 32*kf + 8*q + j.
  // k 0..63 = Wh; k 64..66 = Wi cols (zero padded); k 67 = b_ih+b_hh; k>=68 = 0.
  short8v wf[3][4][3];
  {
    const float* WhA[3] = {Wh3, Wh2, Wh1};
    const float* WiA[3] = {Wi3, Wi2, Wi1};
    const float* biA[3] = {bi3, bi2, bi1};
    const float* bhA[3] = {bh3, bh2, bh1};
    const int wdt[3] = {3, 2, 1};
#pragma unroll
    for (int ty = 0; ty < 3; ++ty) {
#pragma unroll
      for (int g = 0; g < 4; ++g) {
        const int n = 64 * g + 16 * wid + c;  // row of W (4H dim), gate order i,f,g,o
#pragma unroll
        for (int kf = 0; kf < 2; ++kf) {
          short8v v;
#pragma unroll
          for (int j = 0; j < 8; ++j)
            v[j] = f2bf(WhA[ty][n * 64 + kf * 32 + q * 8 + j]);
          wf[ty][g][kf] = v;
        }
        short8v v2 = {0, 0, 0, 0, 0, 0, 0, 0};
        if (q == 0) {
#pragma unroll
          for (int j = 0; j < 3; ++j)
            if (j < wdt[ty]) v2[j] = f2bf(WiA[ty][n * wdt[ty] + j]);
          v2[3] = f2bf(biA[ty][n] + bhA[ty][n]);
        }
        wf[ty][g][2] = v2;
      }
    }
  }

  __syncthreads();  // x1b/x2b/x3b + A-init visible

  auto writeX = [&](int tn, short* wb) {
    if (wid == 0) {
      if (lane < 16) {
        wb[lane * STRIDE + 64] = x1b[lane * 512 + tn];
      } else if (lane < 32) {
        int m = lane - 16;
        wb[m * STRIDE + 65] = x2b[m * 256 + (tn >> 1)];
      } else if (lane < 48) {
        int m = lane - 32;
        wb[m * STRIDE + 66] = x3b[m * 128 + (tn >> 2)];
      }
    }
  };
  writeX(0, A0);
  __syncthreads();

  float cx[4] = {0.f, 0.f, 0.f, 0.f};  // cell state: row 4q+r, col 16*wid+c
  const int abo = c * STRIDE + q * 8;          // A-frag base (m = c, k = 8q+j)
  const int hbo = (q * 4) * STRIDE + wid * 16 + c;  // hx write base

  auto stepf = [&](auto tyc, int t, const short* rbuf, short* wbuf) {
    constexpr int TY = decltype(tyc)::value;
    const short* ab = rbuf + abo;
    short4v p0 = *(const short4v*)(ab);        // 8B-aligned ds_read_b64 pairs
    short4v p1 = *(const short4v*)(ab + 4);
    short4v p2 = *(const short4v*)(ab + 32);
    short4v p3 = *(const short4v*)(ab + 36);
    short4v p4 = *(const short4v*)(ab + 64);
    short4v p5 = *(const short4v*)(ab + 68);
    short8v a0 = __builtin_shufflevector(p0, p1, 0, 1, 2, 3, 4, 5, 6, 7);
    short8v a1 = __builtin_shufflevector(p2, p3, 0, 1, 2, 3, 4, 5, 6, 7);
    short8v a2 = __builtin_shufflevector(p4, p5, 0, 1, 2, 3, 4, 5, 6, 7);

    float4v acc[4];
#pragma unroll
    for (int g = 0; g < 4; ++g) {
      float4v z = {0.f, 0.f, 0.f, 0.f};
      z = __builtin_amdgcn_mfma_f32_16x16x32_bf16(a0, wf[TY][g][0], z, 0, 0, 0);
      z = __builtin_amdgcn_mfma_f32_16x16x32_bf16(a1, wf[TY][g][1], z, 0, 0, 0);
      z = __builtin_amdgcn_mfma_f32_16x16x32_bf16(a2, wf[TY][g][2], z, 0, 0, 0);
      acc[g] = z;
    }

    int tn = t + 1;
    if (tn > 511) tn = 511;  // final write unused
    writeX(tn, wbuf);

    short* hb = wbuf + hbo;
#pragma unroll
    for (int r = 0; r < 4; ++r) {
      float si = fsig(acc[0][r]);
      float sf = fsig(acc[1][r]);
      float tg = ftanh(acc[2][r]);
      float so = fsig(acc[3][r]);
      float ncx = __builtin_fmaf(sf, cx[r], si * tg);
      cx[r] = ncx;
      float hv = so * ftanh(ncx);
      hb[r * STRIDE] = f2bf(hv);
    }
    __syncthreads();  // one barrier per step (double-buffered A)
  };

  // t%4 pattern: 0->ty0, 1->ty2, 2->ty1, 3->ty2 (static unroll, no branches)
  for (int t4 = 0; t4 < 512; t4 += 4) {
    stepf(IC<0>{}, t4, A0, A1);
    stepf(IC<2>{}, t4 + 1, A1, A0);
    stepf(IC<1>{}, t4 + 2, A0, A1);
    stepf(IC<2>{}, t4 + 3, A1, A0);
  }
  // after 512 steps (even), final hx is in A0

  if (tid < 16) {
    float s = bout[0];
    const short* hr = A0 + tid * STRIDE;
#pragma unroll
    for (int k = 0; k < 64; ++k)
      s = __builtin_fmaf(bf2f(hr[k]), Wout[k], s);
    out[R0 + tid] = fsig(s);
  }
}

extern "C" void kernel_launch(void* const* d_in, const int* in_sizes, int n_in,
                              void* d_out, int out_size, void* d_ws,
                              size_t ws_size, hipStream_t stream) {
  const float* x1 = (const float*)d_in[0];
  const float* x2 = (const float*)d_in[1];
  const float* x3 = (const float*)d_in[2];
  const float* Wi3 = (const float*)d_in[3];
  const float* Wh3 = (const float*)d_in[4];
  const float* bi3 = (const float*)d_in[5];
  const float* bh3 = (const float*)d_in[6];
  const float* Wi2 = (const float*)d_in[7];
  const float* Wh2 = (const float*)d_in[8];
  const float* bi2 = (const float*)d_in[9];
  const float* bh2 = (const float*)d_in[10];
  const float* Wi1 = (const float*)d_in[11];
  const float* Wh1 = (const float*)d_in[12];
  const float* bi1 = (const float*)d_in[13];
  const float* bh1 = (const float*)d_in[14];
  const float* Wout = (const float*)d_in[15];
  const float* bout = (const float*)d_in[16];
  float* out = (float*)d_out;

  hipLaunchKernelGGL(mlstm_kernel, dim3(256), dim3(256), 0, stream,
                     x1, x2, x3, Wi3, Wh3, bi3, bh3, Wi2, Wh2, bi2, bh2,
                     Wi1, Wh1, bi1, bh1, Wout, bout, out);
}